// Round 8
// baseline (30.476 us; speedup 1.0000x reference)
//
#include <hip/hip_runtime.h>

#define B 8
#define S 2048
#define NBPS 128                        // inter blocks per sample
#define NBLK_INTER (B * NBPS)           // 1024
#define TPB 256
#define NLOSS_BLK 16                    // 16 x 1024 = 16384 = B*S
#define FP_SCALE 16777216.0f            // 2^24 fixed point
#define CNT_SHIFT 48

typedef unsigned long long ull;

// ---------------------------------------------------------------------------
// Workspace:
//   [0,8)        ull   fused accumulator {count:16 | fixed_sum:48}  (K1 zeroes)
//   [64,96)      int   n_buf[8]
//   [128,448)    float acc2[5][16]     loss per-block sums
//   [512,+128K)  float2 pts_c[8][2048] compacted points
// All cross-kernel traffic crosses a kernel boundary (visibility guaranteed)
// except the fused accumulator, whose count+payload share one atomic word.
// ---------------------------------------------------------------------------

// ================= K1: compaction (8 blocks) + losses (16 blocks) ==========
__global__ __launch_bounds__(1024) void prep_kernel(
    const float4* __restrict__ point_pred4,   // 2 points per float4
    const float2* __restrict__ point_pred,
    const float2* __restrict__ orient_pred,
    const float4* __restrict__ class_pred,
    const float*  __restrict__ target_seq,
    const int*    __restrict__ padding_mask,
    ull*   __restrict__ fused_acc,
    int*   __restrict__ n_buf,
    float* __restrict__ acc2,                 // [5][16]
    float2* __restrict__ pts_c)
{
    const int blk = blockIdx.x;
    const int tid = threadIdx.x;
    const int lane = tid & 63, wv = tid >> 6;

    if (blk == 0 && tid == 0) *fused_acc = 0ull;

    if (blk < B) {
        // ---------- stable compaction of sample blk ----------
        const int b = blk;
        const int base = b * S;
        const int2* pm2 = (const int2*)(padding_mask + base);
        const int2 mk = pm2[tid];
        const float t4a = target_seq[(size_t)(base + tid * 2 + 0) * 5 + 4];
        const float t4b = target_seq[(size_t)(base + tid * 2 + 1) * 5 + 4];
        const float4 pp = point_pred4[(base >> 1) + tid];
        const int f0 = (mk.x == 0 && (int)t4a != 0) ? 1 : 0;
        const int f1 = (mk.y == 0 && (int)t4b != 0) ? 1 : 0;

        __shared__ int wsum[16], woff[16];
        const int tsum = f0 + f1;
        int inc = tsum;
        #pragma unroll
        for (int off = 1; off < 64; off <<= 1) {
            int u = __shfl_up(inc, (unsigned)off, 64);
            if (lane >= off) inc += u;
        }
        if (lane == 63) wsum[wv] = inc;
        __syncthreads();
        if (tid == 0) {
            int run = 0;
            #pragma unroll
            for (int w = 0; w < 16; ++w) { woff[w] = run; run += wsum[w]; }
            n_buf[b] = run;
        }
        __syncthreads();
        const int pos = base + woff[wv] + (inc - tsum);
        if (f0) pts_c[pos] = make_float2(pp.x, pp.y);
        if (f1) pts_c[pos + f0] = make_float2(pp.z, pp.w);
    } else {
        // ---------- per-element losses: 16 blocks x 1024 elems ----------
        const int lb = blk - B;               // [0,16)
        const int idx = lb * 1024 + tid;      // [0, B*S)
        const bool valid = (padding_mask[idx] == 0);
        const float t4 = target_seq[(size_t)idx * 5 + 4];
        const int tc = (int)t4;
        const bool nn = valid && (tc != 0);
        float cls_a = 0.f, pt_a = 0.f, or_a = 0.f, v_a = 0.f, nn_a = 0.f;
        if (valid) {
            const float4 cl = class_pred[idx];
            const float m = fmaxf(fmaxf(cl.x, cl.y), fmaxf(cl.z, cl.w));
            const float lse = m + logf(expf(cl.x - m) + expf(cl.y - m) +
                                       expf(cl.z - m) + expf(cl.w - m));
            const float ct = (tc == 0) ? cl.x : (tc == 1) ? cl.y : (tc == 2) ? cl.z : cl.w;
            cls_a = lse - ct;
            v_a = 1.f;
        }
        if (nn) {
            const float2 pp = point_pred[idx];
            const float tx = target_seq[(size_t)idx * 5 + 0];
            const float ty = target_seq[(size_t)idx * 5 + 1];
            const float dx = (pp.x - tx) * (1.0f / 224.0f);
            const float dy = (pp.y - ty) * (1.0f / 224.0f);
            const float adx = fabsf(dx), ady = fabsf(dy);
            const float l0 = (adx < 1.f) ? 0.5f * dx * dx : adx - 0.5f;
            const float l1 = (ady < 1.f) ? 0.5f * dy * dy : ady - 0.5f;
            pt_a = 0.5f * (l0 + l1);
            const float2 op = orient_pred[idx];
            const float ox = target_seq[(size_t)idx * 5 + 2];
            const float oy = target_seq[(size_t)idx * 5 + 3];
            or_a = 1.f - (op.x * ox + op.y * oy);
            nn_a = 1.f;
        }
        __shared__ float red[16][5];
        #pragma unroll
        for (int off = 32; off > 0; off >>= 1) {
            cls_a += __shfl_down(cls_a, (unsigned)off, 64);
            pt_a  += __shfl_down(pt_a,  (unsigned)off, 64);
            or_a  += __shfl_down(or_a,  (unsigned)off, 64);
            v_a   += __shfl_down(v_a,   (unsigned)off, 64);
            nn_a  += __shfl_down(nn_a,  (unsigned)off, 64);
        }
        if (lane == 0) {
            red[wv][0] = cls_a; red[wv][1] = pt_a; red[wv][2] = or_a;
            red[wv][3] = v_a;   red[wv][4] = nn_a;
        }
        __syncthreads();
        if (tid == 0) {
            float s0 = 0, s1 = 0, s2 = 0, s3 = 0, s4 = 0;
            #pragma unroll
            for (int w = 0; w < 16; ++w) {
                s0 += red[w][0]; s1 += red[w][1]; s2 += red[w][2];
                s3 += red[w][3]; s4 += red[w][4];
            }
            acc2[0 * NLOSS_BLK + lb] = s0;
            acc2[1 * NLOSS_BLK + lb] = s1;
            acc2[2 * NLOSS_BLK + lb] = s2;
            acc2[3 * NLOSS_BLK + lb] = s3;
            acc2[4 * NLOSS_BLK + lb] = s4;
        }
    }
}

// ================= K2: intersection (1024 blocks) + finalizer (1) ==========
__global__ __launch_bounds__(TPB) void inter_kernel(
    const float2* __restrict__ pts_c,
    const int*   __restrict__ n_buf,
    const float* __restrict__ acc2,
    ull*   __restrict__ fused_acc,
    float* __restrict__ out)
{
    const int blk = blockIdx.x;
    const int tid = threadIdx.x;
    const int lane = tid & 63, wv = tid >> 6;

    if (blk < NBLK_INTER) {
        // ---------------- intersection role ----------------
        __shared__ float2 sp[S];             // 16 KB
        __shared__ float red[TPB / 64];
        const int b = blk >> 7;              // blk / NBPS
        const int iblk = blk & (NBPS - 1);
        const int n = n_buf[b];
        float local = 0.f;
        if (n >= 4) {                        // uniform across block
            const int n_seg = n - 1;
            const float2* pb = pts_c + b * S;
            for (int k = tid; k < n; k += TPB) sp[k] = pb[k];
            __syncthreads();
            for (int i = iblk; i < n_seg - 2; i += NBPS) {
                const float2 q1 = sp[i], q2 = sp[i + 1];
                const float e12x = q2.x - q1.x, e12y = q2.y - q1.y;
                const int jmax = (i == 0) ? n_seg - 1 : n_seg;  // wrap excl.
                for (int j = i + 2 + tid; j < jmax; j += TPB) {
                    const float2 q3 = sp[j], q4 = sp[j + 1];
                    const float e34x = q4.x - q3.x, e34y = q4.y - q3.y;
                    const float ce = e12x * e34y - e12y * e34x;
                    const float rx = q1.x - q3.x, ry = q1.y - q3.y;
                    const float d1 = e34x * ry - e34y * rx;
                    const float d3 = e12y * rx - e12x * ry;
                    const float d2 = d1 - ce;
                    const float d4 = d3 + ce;
                    const float ea = __expf(d1 * d2 * 0.01f);
                    const float eb = __expf(d3 * d4 * 0.01f);
                    // sigmoid(z1)*sigmoid(z2)=1/((1+ea)(1+eb)); inf->rcp->0 ok
                    local += __builtin_amdgcn_rcpf((1.f + ea) * (1.f + eb));
                }
            }
        }
        #pragma unroll
        for (int off = 32; off > 0; off >>= 1)
            local += __shfl_down(local, (unsigned)off, 64);
        if (lane == 0) red[wv] = local;
        __syncthreads();
        if (tid == 0) {
            const float bsum = red[0] + red[1] + red[2] + red[3];
            // fused {count+1 : fixed_sum+=bsum*2^24} in ONE u64 atomic:
            // integer add = exact & associative -> deterministic, no fences.
            const ull payload = ((ull)1 << CNT_SHIFT) + (ull)(bsum * FP_SCALE);
            atomicAdd(fused_acc, payload);
        }
    } else {
        // ---------------- finalizer role (1 block, wave 0 only) ----------
        if (wv != 0) return;
        // spin on the single fused word until all 1024 blocks arrived
        ull w;
        do {
            w = __hip_atomic_load(fused_acc, __ATOMIC_RELAXED,
                                  __HIP_MEMORY_SCOPE_AGENT);
        } while ((w >> CNT_SHIFT) != (ull)NBLK_INTER);
        const float inter_sum =
            (float)((double)(w & (((ull)1 << CNT_SHIFT) - 1)) *
                    (1.0 / (double)FP_SCALE));

        // loss channels: lanes 0..15 hold acc2 slots, reduce in-wave
        float a[5] = {0.f, 0.f, 0.f, 0.f, 0.f};
        if (lane < NLOSS_BLK) {
            #pragma unroll
            for (int ch = 0; ch < 5; ++ch)
                a[ch] = acc2[ch * NLOSS_BLK + lane];
        }
        #pragma unroll
        for (int off = 8; off > 0; off >>= 1) {
            #pragma unroll
            for (int ch = 0; ch < 5; ++ch)
                a[ch] += __shfl_down(a[ch], (unsigned)off, 64);
        }

        if (lane == 0) {
            long long cnt = 0;
            #pragma unroll
            for (int b2 = 0; b2 < B; ++b2) {
                const int n = n_buf[b2];
                if (n >= 4) {
                    const long long ns = n - 1;
                    cnt += (ns - 1) * (ns - 2) / 2 - 1;
                }
            }
            const float cls_loss = a[0] / fmaxf(a[3], 1.f);
            const float pt_loss = a[1] / fmaxf(a[4], 1.f);
            const float orient_loss = a[2] / fmaxf(a[4], 1.f);
            const float intersect_loss = (cnt > 0) ? inter_sum / (float)cnt : 0.f;
            out[0] = 1.0f * pt_loss + 0.5f * orient_loss +
                     1.0f * cls_loss + 0.1f * intersect_loss;
            out[1] = pt_loss;
            out[2] = orient_loss;
            out[3] = cls_loss;
            out[4] = intersect_loss;
        }
    }
}

extern "C" void kernel_launch(void* const* d_in, const int* in_sizes, int n_in,
                              void* d_out, int out_size, void* d_ws, size_t ws_size,
                              hipStream_t stream) {
    (void)in_sizes; (void)n_in; (void)out_size; (void)ws_size;
    const float2* point_pred  = (const float2*)d_in[0];
    const float2* orient_pred = (const float2*)d_in[1];
    const float4* class_pred  = (const float4*)d_in[2];
    const float*  target_seq  = (const float*)d_in[3];
    const int*    padding_mask = (const int*)d_in[4];

    ull*    fused_acc = (ull*)d_ws;
    int*    n_buf     = (int*)((char*)d_ws + 64);
    float*  acc2      = (float*)((char*)d_ws + 128);
    float2* pts_c     = (float2*)((char*)d_ws + 512);

    prep_kernel<<<B + NLOSS_BLK, 1024, 0, stream>>>(
        (const float4*)point_pred, point_pred, orient_pred, class_pred,
        target_seq, padding_mask, fused_acc, n_buf, acc2, pts_c);
    inter_kernel<<<NBLK_INTER + 1, TPB, 0, stream>>>(
        pts_c, n_buf, acc2, fused_acc, (float*)d_out);
}

// Round 9
// 19.967 us; speedup vs baseline: 1.5263x; 1.5263x over previous
//
#include <hip/hip_runtime.h>

#define B 8
#define S 2048
#define NBPS 128                        // inter blocks per sample
#define NBLK_INTER (B * NBPS)           // 1024
#define NBLK_LOSS 64                    // 64 x 256 = 16384 = B*S
#define NBLK_TOTAL (NBLK_INTER + NBLK_LOSS + 1)   // +1 finalizer
#define TPB 256
#define MAGIC 0xA5C97E31u

typedef unsigned long long ull;
typedef unsigned int uint;

// ---------------------------------------------------------------------------
// Tagged 64-bit slots: {tag:32 | payload:32}, relaxed agent-scope atomics.
// Hierarchical sync: workers -> 8 sample-masters -> 1 finalizer. Every
// spinning thread waits on <=2 slots (R7's failure was 4-5 deep sequential
// waits on one block). Only 9 blocks spin; spin graph is a DAG over
// non-spinning workers -> no deadlock at any occupancy. All tags cleared by
// their consumer (re-poison safe: 0xAAAAAAAA != MAGIC; stream order covers
// replay N -> N+1).
// Slot layout in d_ws (ull[]):
//   [0,1024)     partial  : worker inter sums (masters' own 8 slots unused)
//   [1024,1032)  master   : per-sample inter sums
//   [1032,1040)  nbuf     : per-sample compacted counts
//   [1040,1360)  loss     : ch*64+lb
// ---------------------------------------------------------------------------
__device__ __forceinline__ void slot_store(ull* p, uint payload) {
    __hip_atomic_store(p, ((ull)MAGIC << 32) | (ull)payload,
                       __ATOMIC_RELAXED, __HIP_MEMORY_SCOPE_AGENT);
}
__device__ __forceinline__ uint slot_wait(ull* p) {
    ull w;
    do {
        w = __hip_atomic_load(p, __ATOMIC_RELAXED, __HIP_MEMORY_SCOPE_AGENT);
    } while ((uint)(w >> 32) != MAGIC);
    return (uint)w;
}
__device__ __forceinline__ void slot_clear(ull* p) {
    __hip_atomic_store(p, 0ull, __ATOMIC_RELAXED, __HIP_MEMORY_SCOPE_AGENT);
}

__global__ __launch_bounds__(TPB) void mega_kernel(
    const float2* __restrict__ point_pred,
    const float2* __restrict__ orient_pred,
    const float4* __restrict__ class_pred,
    const float*  __restrict__ target_seq,
    const int*    __restrict__ padding_mask,
    ull* __restrict__ slots,
    float* __restrict__ out)
{
    __shared__ float2 sp[S];                 // 16 KB
    __shared__ float redf[TPB / 64][5];
    __shared__ int wsum[TPB / 64], woff[TPB / 64], nTot;

    ull* sl_partial = slots;
    ull* sl_master  = slots + NBLK_INTER;
    ull* sl_nbuf    = slots + NBLK_INTER + 8;
    ull* sl_loss    = slots + NBLK_INTER + 16;

    const int blk = blockIdx.x;
    const int tid = threadIdx.x;
    const int lane = tid & 63, wv = tid >> 6;

    if (blk < NBLK_INTER) {
        // ================= intersection role (R6-proven body) ============
        const int b = blk >> 7;
        const int iblk = blk & (NBPS - 1);
        const int base = b * S;
        const int e0 = tid * 8;

        const int4* pm4 = (const int4*)(padding_mask + base + e0);
        const int4 ma = pm4[0], mb = pm4[1];
        const float4* tr4 = (const float4*)(target_seq + (size_t)(base + e0) * 5);
        float4 tq[10];
        #pragma unroll
        for (int k = 0; k < 10; ++k) tq[k] = tr4[k];
        float t4v[8];
        t4v[0] = tq[1].x; t4v[1] = tq[2].y; t4v[2] = tq[3].z; t4v[3] = tq[4].w;
        t4v[4] = tq[6].x; t4v[5] = tq[7].y; t4v[6] = tq[8].z; t4v[7] = tq[9].w;
        const float4* pq4 = (const float4*)(point_pred + base + e0);
        const float4 pa = pq4[0], pb = pq4[1], pc = pq4[2], pd = pq4[3];
        float2 p[8];
        p[0] = make_float2(pa.x, pa.y); p[1] = make_float2(pa.z, pa.w);
        p[2] = make_float2(pb.x, pb.y); p[3] = make_float2(pb.z, pb.w);
        p[4] = make_float2(pc.x, pc.y); p[5] = make_float2(pc.z, pc.w);
        p[6] = make_float2(pd.x, pd.y); p[7] = make_float2(pd.z, pd.w);
        int f[8];
        f[0] = (ma.x == 0 && (int)t4v[0] != 0) ? 1 : 0;
        f[1] = (ma.y == 0 && (int)t4v[1] != 0) ? 1 : 0;
        f[2] = (ma.z == 0 && (int)t4v[2] != 0) ? 1 : 0;
        f[3] = (ma.w == 0 && (int)t4v[3] != 0) ? 1 : 0;
        f[4] = (mb.x == 0 && (int)t4v[4] != 0) ? 1 : 0;
        f[5] = (mb.y == 0 && (int)t4v[5] != 0) ? 1 : 0;
        f[6] = (mb.z == 0 && (int)t4v[6] != 0) ? 1 : 0;
        f[7] = (mb.w == 0 && (int)t4v[7] != 0) ? 1 : 0;

        const int c = f[0]+f[1]+f[2]+f[3]+f[4]+f[5]+f[6]+f[7];
        int inc = c;
        #pragma unroll
        for (int off = 1; off < 64; off <<= 1) {
            int u = __shfl_up(inc, (unsigned)off, 64);
            if (lane >= off) inc += u;
        }
        if (lane == 63) wsum[wv] = inc;
        __syncthreads();
        if (tid == 0) {
            int run = 0;
            #pragma unroll
            for (int w = 0; w < TPB / 64; ++w) { woff[w] = run; run += wsum[w]; }
            nTot = run;
        }
        __syncthreads();
        int pos = woff[wv] + inc - c;
        #pragma unroll
        for (int k = 0; k < 8; ++k) { if (f[k]) sp[pos++] = p[k]; }
        __syncthreads();

        const int n = nTot;
        float local = 0.f;
        if (n >= 4) {
            const int n_seg = n - 1;
            for (int i = iblk; i < n_seg - 2; i += NBPS) {
                const float2 q1 = sp[i], q2 = sp[i + 1];
                const float e12x = q2.x - q1.x, e12y = q2.y - q1.y;
                const int jmax = (i == 0) ? n_seg - 1 : n_seg;  // wrap excl.
                for (int j = i + 2 + tid; j < jmax; j += TPB) {
                    const float2 q3 = sp[j], q4 = sp[j + 1];
                    const float e34x = q4.x - q3.x, e34y = q4.y - q3.y;
                    const float ce = e12x * e34y - e12y * e34x;
                    const float rx = q1.x - q3.x, ry = q1.y - q3.y;
                    const float d1 = e34x * ry - e34y * rx;
                    const float d3 = e12y * rx - e12x * ry;
                    const float d2 = d1 - ce;
                    const float d4 = d3 + ce;
                    const float ea = __expf(d1 * d2 * 0.01f);
                    const float eb = __expf(d3 * d4 * 0.01f);
                    // sigmoid(z1)*sigmoid(z2)=1/((1+ea)(1+eb)); inf->rcp->0 ok
                    local += __builtin_amdgcn_rcpf((1.f + ea) * (1.f + eb));
                }
            }
        }
        #pragma unroll
        for (int off = 32; off > 0; off >>= 1)
            local += __shfl_down(local, (unsigned)off, 64);
        if (lane == 0) redf[wv][0] = local;
        __syncthreads();

        if (iblk != 0) {
            // ---- plain worker: publish one tagged slot ----
            if (tid == 0)
                slot_store(&sl_partial[blk],
                           __float_as_uint(redf[0][0] + redf[1][0] +
                                           redf[2][0] + redf[3][0]));
        } else {
            // ---- sample master: collect 127 siblings (1 slot/thread) ----
            float val = 0.f;
            if (tid == 0)
                val = redf[0][0] + redf[1][0] + redf[2][0] + redf[3][0];
            __syncthreads();                 // protect redf before reuse
            if (tid >= 1 && tid < NBPS) {
                ull* sl = &sl_partial[blk + tid];
                val = __uint_as_float(slot_wait(sl));
                slot_clear(sl);
            }
            #pragma unroll
            for (int off = 32; off > 0; off >>= 1)
                val += __shfl_down(val, (unsigned)off, 64);
            if (lane == 0) redf[wv][0] = val;
            __syncthreads();
            if (tid == 0) {
                slot_store(&sl_master[b],
                           __float_as_uint(redf[0][0] + redf[1][0]));
                slot_store(&sl_nbuf[b], (uint)n);
            }
        }
    } else if (blk < NBLK_INTER + NBLK_LOSS) {
        // ================= per-element loss role =================
        const int lb = blk - NBLK_INTER;     // [0,64)
        const int idx = lb * TPB + tid;      // [0, B*S)
        const bool valid = (padding_mask[idx] == 0);
        const float t4 = target_seq[(size_t)idx * 5 + 4];
        const int tc = (int)t4;
        const bool nn = valid && (tc != 0);
        float cls_a = 0.f, pt_a = 0.f, or_a = 0.f, v_a = 0.f, nn_a = 0.f;
        if (valid) {
            const float4 cl = class_pred[idx];
            const float m = fmaxf(fmaxf(cl.x, cl.y), fmaxf(cl.z, cl.w));
            const float lse = m + logf(expf(cl.x - m) + expf(cl.y - m) +
                                       expf(cl.z - m) + expf(cl.w - m));
            const float ct = (tc == 0) ? cl.x : (tc == 1) ? cl.y : (tc == 2) ? cl.z : cl.w;
            cls_a = lse - ct;
            v_a = 1.f;
        }
        if (nn) {
            const float2 pp = point_pred[idx];
            const float tx = target_seq[(size_t)idx * 5 + 0];
            const float ty = target_seq[(size_t)idx * 5 + 1];
            const float dx = (pp.x - tx) * (1.0f / 224.0f);
            const float dy = (pp.y - ty) * (1.0f / 224.0f);
            const float adx = fabsf(dx), ady = fabsf(dy);
            const float l0 = (adx < 1.f) ? 0.5f * dx * dx : adx - 0.5f;
            const float l1 = (ady < 1.f) ? 0.5f * dy * dy : ady - 0.5f;
            pt_a = 0.5f * (l0 + l1);
            const float2 op = orient_pred[idx];
            const float ox = target_seq[(size_t)idx * 5 + 2];
            const float oy = target_seq[(size_t)idx * 5 + 3];
            or_a = 1.f - (op.x * ox + op.y * oy);
            nn_a = 1.f;
        }
        #pragma unroll
        for (int off = 32; off > 0; off >>= 1) {
            cls_a += __shfl_down(cls_a, (unsigned)off, 64);
            pt_a  += __shfl_down(pt_a,  (unsigned)off, 64);
            or_a  += __shfl_down(or_a,  (unsigned)off, 64);
            v_a   += __shfl_down(v_a,   (unsigned)off, 64);
            nn_a  += __shfl_down(nn_a,  (unsigned)off, 64);
        }
        if (lane == 0) {
            redf[wv][0] = cls_a; redf[wv][1] = pt_a; redf[wv][2] = or_a;
            redf[wv][3] = v_a;   redf[wv][4] = nn_a;
        }
        __syncthreads();
        if (tid == 0) {
            #pragma unroll
            for (int c5 = 0; c5 < 5; ++c5)
                slot_store(&sl_loss[c5 * NBLK_LOSS + lb],
                           __float_as_uint(redf[0][c5] + redf[1][c5] +
                                           redf[2][c5] + redf[3][c5]));
        }
    } else {
        // ================= finalizer (<=2 sequential waits/thread) =======
        __shared__ float fs[B];
        __shared__ int fn[B];
        __shared__ float chs[5];

        if (tid < B) {
            ull* pm = &sl_master[tid];
            ull* pn = &sl_nbuf[tid];
            fs[tid] = __uint_as_float(slot_wait(pm)); slot_clear(pm);
            fn[tid] = (int)slot_wait(pn);             slot_clear(pn);
        }
        // loss slots: tid waits sl_loss[tid] (ch=wv, lb=lane); wave0 also
        // waits sl_loss[256+lane] (channel 4).
        ull* pl0 = &sl_loss[tid];
        float lv0 = __uint_as_float(slot_wait(pl0)); slot_clear(pl0);
        float lv1 = 0.f;
        if (tid < 64) {
            ull* pl1 = &sl_loss[256 + tid];
            lv1 = __uint_as_float(slot_wait(pl1)); slot_clear(pl1);
        }
        #pragma unroll
        for (int off = 32; off > 0; off >>= 1) {
            lv0 += __shfl_down(lv0, (unsigned)off, 64);
            lv1 += __shfl_down(lv1, (unsigned)off, 64);
        }
        if (lane == 0) chs[wv] = lv0;          // channels 0..3
        if (tid == 0) chs[4] = lv1;            // wave0 second pass
        __syncthreads();

        if (tid == 0) {
            float inter_sum = 0.f;
            #pragma unroll
            for (int b2 = 0; b2 < B; ++b2) inter_sum += fs[b2];
            long long cnt = 0;
            #pragma unroll
            for (int b2 = 0; b2 < B; ++b2) {
                const int n = fn[b2];
                if (n >= 4) {
                    const long long ns = n - 1;
                    cnt += (ns - 1) * (ns - 2) / 2 - 1;
                }
            }
            const float cls_loss = chs[0] / fmaxf(chs[3], 1.f);
            const float pt_loss = chs[1] / fmaxf(chs[4], 1.f);
            const float orient_loss = chs[2] / fmaxf(chs[4], 1.f);
            const float intersect_loss = (cnt > 0) ? inter_sum / (float)cnt : 0.f;
            out[0] = 1.0f * pt_loss + 0.5f * orient_loss +
                     1.0f * cls_loss + 0.1f * intersect_loss;
            out[1] = pt_loss;
            out[2] = orient_loss;
            out[3] = cls_loss;
            out[4] = intersect_loss;
        }
    }
}

extern "C" void kernel_launch(void* const* d_in, const int* in_sizes, int n_in,
                              void* d_out, int out_size, void* d_ws, size_t ws_size,
                              hipStream_t stream) {
    (void)in_sizes; (void)n_in; (void)out_size; (void)ws_size;
    const float2* point_pred  = (const float2*)d_in[0];
    const float2* orient_pred = (const float2*)d_in[1];
    const float4* class_pred  = (const float4*)d_in[2];
    const float*  target_seq  = (const float*)d_in[3];
    const int*    padding_mask = (const int*)d_in[4];

    mega_kernel<<<NBLK_TOTAL, TPB, 0, stream>>>(point_pred, orient_pred,
                                                class_pred, target_seq,
                                                padding_mask,
                                                (ull*)d_ws, (float*)d_out);
}

// Round 10
// 17.993 us; speedup vs baseline: 1.6938x; 1.1097x over previous
//
#include <hip/hip_runtime.h>

#define B 8
#define S 2048
#define NBPS 64                         // inter blocks per sample
#define NBLK_INTER (B * NBPS)           // 512
#define NBLK_LOSS 32                    // 32 x 512 = 16384 = B*S
#define NBLK_TOTAL (NBLK_INTER + NBLK_LOSS)   // 544
#define TPB 512
#define NW (TPB / 64)                   // 8 waves

// ---------------------------------------------------------------------------
// Workspace (every slot rewritten every launch -> re-poison safe, no atomics):
//   [0,32)       int   n_buf[8]
//   [64,2112)    float partial[512]    intersection per-block sums
//   [2176,2816)  float acc2[5][32]     loss per-block sums (transposed)
// ---------------------------------------------------------------------------

__global__ __launch_bounds__(TPB) void mega_kernel(
    const float2* __restrict__ point_pred,
    const float2* __restrict__ orient_pred,
    const float4* __restrict__ class_pred,
    const float*  __restrict__ target_seq,
    const int*    __restrict__ padding_mask,
    int*   __restrict__ n_buf,
    float* __restrict__ partial,    // [512]
    float* __restrict__ acc2)       // [5][32]
{
    __shared__ float2 sp[S];                 // 16 KB
    __shared__ float redf[NW][5];
    __shared__ int wsum[NW], woff[NW], nTot;

    const int blk = blockIdx.x;
    const int tid = threadIdx.x;
    const int lane = tid & 63, wv = tid >> 6;

    if (blk < NBLK_INTER) {
        // ================= intersection role =================
        const int b = blk >> 6;              // blk / NBPS
        const int iblk = blk & (NBPS - 1);
        const int base = b * S;
        const int e0 = tid * 4;              // 4 contiguous elems per thread

        // ---- staged loads: mask (int4), target rows (float4 x5),
        //      points (float4 x2) ----
        const int4 ma = *(const int4*)(padding_mask + base + e0);
        const float4* tr4 = (const float4*)(target_seq + (size_t)(base + e0) * 5);
        float4 tq[5];
        #pragma unroll
        for (int k = 0; k < 5; ++k) tq[k] = tr4[k];
        float t4v[4];
        t4v[0] = tq[1].x; t4v[1] = tq[2].y; t4v[2] = tq[3].z; t4v[3] = tq[4].w;
        const float4* pq4 = (const float4*)(point_pred + base + e0);
        const float4 pa = pq4[0], pb = pq4[1];
        float2 p[4];
        p[0] = make_float2(pa.x, pa.y); p[1] = make_float2(pa.z, pa.w);
        p[2] = make_float2(pb.x, pb.y); p[3] = make_float2(pb.z, pb.w);
        int f[4];
        f[0] = (ma.x == 0 && (int)t4v[0] != 0) ? 1 : 0;
        f[1] = (ma.y == 0 && (int)t4v[1] != 0) ? 1 : 0;
        f[2] = (ma.z == 0 && (int)t4v[2] != 0) ? 1 : 0;
        f[3] = (ma.w == 0 && (int)t4v[3] != 0) ? 1 : 0;

        // ---- block scan over per-thread counts (stable compaction) ----
        const int c = f[0] + f[1] + f[2] + f[3];
        int inc = c;
        #pragma unroll
        for (int off = 1; off < 64; off <<= 1) {
            int u = __shfl_up(inc, (unsigned)off, 64);
            if (lane >= off) inc += u;
        }
        if (lane == 63) wsum[wv] = inc;
        __syncthreads();
        if (tid == 0) {
            int run = 0;
            #pragma unroll
            for (int w = 0; w < NW; ++w) { woff[w] = run; run += wsum[w]; }
            nTot = run;
        }
        __syncthreads();
        int pos = woff[wv] + inc - c;        // exclusive prefix
        #pragma unroll
        for (int k = 0; k < 4; ++k) { if (f[k]) sp[pos++] = p[k]; }
        __syncthreads();

        const int n = nTot;
        if (iblk == 0 && tid == 0) n_buf[b] = n;

        // ---- pair loop ----
        float local = 0.f;
        if (n >= 4) {
            const int n_seg = n - 1;
            for (int i = iblk; i < n_seg - 2; i += NBPS) {
                const float2 q1 = sp[i], q2 = sp[i + 1];
                const float e12x = q2.x - q1.x, e12y = q2.y - q1.y;
                const int jmax = (i == 0) ? n_seg - 1 : n_seg;  // wrap excl.
                for (int j = i + 2 + tid; j < jmax; j += TPB) {
                    const float2 q3 = sp[j], q4 = sp[j + 1];
                    const float e34x = q4.x - q3.x, e34y = q4.y - q3.y;
                    const float ce = e12x * e34y - e12y * e34x;
                    const float rx = q1.x - q3.x, ry = q1.y - q3.y;
                    const float d1 = e34x * ry - e34y * rx;
                    const float d3 = e12y * rx - e12x * ry;
                    const float d2 = d1 - ce;
                    const float d4 = d3 + ce;
                    const float ea = __expf(d1 * d2 * 0.01f);
                    const float eb = __expf(d3 * d4 * 0.01f);
                    // sigmoid(z1)*sigmoid(z2)=1/((1+ea)(1+eb)); inf->rcp->0 ok
                    local += __builtin_amdgcn_rcpf((1.f + ea) * (1.f + eb));
                }
            }
        }
        #pragma unroll
        for (int off = 32; off > 0; off >>= 1)
            local += __shfl_down(local, (unsigned)off, 64);
        if (lane == 0) redf[wv][0] = local;
        __syncthreads();
        if (tid == 0) {
            float s = 0.f;
            #pragma unroll
            for (int w = 0; w < NW; ++w) s += redf[w][0];
            partial[blk] = s;
        }
    } else {
        // ================= per-element loss role =================
        const int lb = blk - NBLK_INTER;     // [0,32)
        const int idx = lb * TPB + tid;      // [0, B*S)
        const bool valid = (padding_mask[idx] == 0);
        const float t4 = target_seq[(size_t)idx * 5 + 4];
        const int tc = (int)t4;
        const bool nn = valid && (tc != 0);
        float cls_a = 0.f, pt_a = 0.f, or_a = 0.f, v_a = 0.f, nn_a = 0.f;
        if (valid) {
            const float4 cl = class_pred[idx];
            const float m = fmaxf(fmaxf(cl.x, cl.y), fmaxf(cl.z, cl.w));
            const float lse = m + logf(expf(cl.x - m) + expf(cl.y - m) +
                                       expf(cl.z - m) + expf(cl.w - m));
            const float ct = (tc == 0) ? cl.x : (tc == 1) ? cl.y : (tc == 2) ? cl.z : cl.w;
            cls_a = lse - ct;
            v_a = 1.f;
        }
        if (nn) {
            const float2 pp = point_pred[idx];
            const float tx = target_seq[(size_t)idx * 5 + 0];
            const float ty = target_seq[(size_t)idx * 5 + 1];
            const float dx = (pp.x - tx) * (1.0f / 224.0f);
            const float dy = (pp.y - ty) * (1.0f / 224.0f);
            const float adx = fabsf(dx), ady = fabsf(dy);
            const float l0 = (adx < 1.f) ? 0.5f * dx * dx : adx - 0.5f;
            const float l1 = (ady < 1.f) ? 0.5f * dy * dy : ady - 0.5f;
            pt_a = 0.5f * (l0 + l1);
            const float2 op = orient_pred[idx];
            const float ox = target_seq[(size_t)idx * 5 + 2];
            const float oy = target_seq[(size_t)idx * 5 + 3];
            or_a = 1.f - (op.x * ox + op.y * oy);
            nn_a = 1.f;
        }
        #pragma unroll
        for (int off = 32; off > 0; off >>= 1) {
            cls_a += __shfl_down(cls_a, (unsigned)off, 64);
            pt_a  += __shfl_down(pt_a,  (unsigned)off, 64);
            or_a  += __shfl_down(or_a,  (unsigned)off, 64);
            v_a   += __shfl_down(v_a,   (unsigned)off, 64);
            nn_a  += __shfl_down(nn_a,  (unsigned)off, 64);
        }
        if (lane == 0) {
            redf[wv][0] = cls_a; redf[wv][1] = pt_a; redf[wv][2] = or_a;
            redf[wv][3] = v_a;   redf[wv][4] = nn_a;
        }
        __syncthreads();
        if (tid == 0) {
            #pragma unroll
            for (int c5 = 0; c5 < 5; ++c5) {
                float s = 0.f;
                #pragma unroll
                for (int w = 0; w < NW; ++w) s += redf[w][c5];
                acc2[c5 * NBLK_LOSS + lb] = s;
            }
        }
    }
}

// ---------------------------------------------------------------------------
// Finalize: 1 wave, no barriers. Kernel boundary = cross-XCD visibility.
// ---------------------------------------------------------------------------
__global__ __launch_bounds__(64) void finalize_kernel(
    const float* __restrict__ acc2,      // [5][32]
    const int* __restrict__ n_buf,
    const float* __restrict__ partial,   // [512]
    float* __restrict__ out)
{
    const int lane = threadIdx.x;        // 0..63

    const float4* p4 = (const float4*)partial;   // 128 float4
    const float4 u = p4[lane * 2], v = p4[lane * 2 + 1];
    float s = (u.x + u.y) + (u.z + u.w) + (v.x + v.y) + (v.z + v.w);

    float a[5] = {0.f, 0.f, 0.f, 0.f, 0.f};
    if (lane < NBLK_LOSS) {
        #pragma unroll
        for (int ch = 0; ch < 5; ++ch) a[ch] = acc2[ch * NBLK_LOSS + lane];
    }

    #pragma unroll
    for (int off = 32; off > 0; off >>= 1) {
        s += __shfl_down(s, (unsigned)off, 64);
        #pragma unroll
        for (int ch = 0; ch < 5; ++ch)
            a[ch] += __shfl_down(a[ch], (unsigned)off, 64);
    }

    if (lane == 0) {
        const float inter_sum = s;
        long long cnt = 0;
        #pragma unroll
        for (int b2 = 0; b2 < B; ++b2) {
            const int n = n_buf[b2];
            if (n >= 4) {
                const long long ns = n - 1;
                cnt += (ns - 1) * (ns - 2) / 2 - 1;
            }
        }
        const float cls_loss = a[0] / fmaxf(a[3], 1.f);
        const float pt_loss = a[1] / fmaxf(a[4], 1.f);
        const float orient_loss = a[2] / fmaxf(a[4], 1.f);
        const float intersect_loss = (cnt > 0) ? inter_sum / (float)cnt : 0.f;
        out[0] = 1.0f * pt_loss + 0.5f * orient_loss +
                 1.0f * cls_loss + 0.1f * intersect_loss;
        out[1] = pt_loss;
        out[2] = orient_loss;
        out[3] = cls_loss;
        out[4] = intersect_loss;
    }
}

extern "C" void kernel_launch(void* const* d_in, const int* in_sizes, int n_in,
                              void* d_out, int out_size, void* d_ws, size_t ws_size,
                              hipStream_t stream) {
    (void)in_sizes; (void)n_in; (void)out_size; (void)ws_size;
    const float2* point_pred  = (const float2*)d_in[0];
    const float2* orient_pred = (const float2*)d_in[1];
    const float4* class_pred  = (const float4*)d_in[2];
    const float*  target_seq  = (const float*)d_in[3];
    const int*    padding_mask = (const int*)d_in[4];

    int*   n_buf   = (int*)d_ws;
    float* partial = (float*)((char*)d_ws + 64);
    float* acc2    = (float*)((char*)d_ws + 2176);

    mega_kernel<<<NBLK_TOTAL, TPB, 0, stream>>>(point_pred, orient_pred,
                                                class_pred, target_seq,
                                                padding_mask,
                                                n_buf, partial, acc2);
    finalize_kernel<<<1, 64, 0, stream>>>(acc2, n_buf, partial, (float*)d_out);
}